// Round 5
// baseline (286.149 us; speedup 1.0000x reference)
//
#include <hip/hip_runtime.h>
#include <hip/hip_bf16.h>

#define Bv 4
#define Tv 2048
#define Dv 1024
#define Hv 16
#define HDv 64
#define Mv (Bv*Tv)   // 8192

typedef __hip_bfloat16 bf16;
typedef short s8v __attribute__((ext_vector_type(8)));
typedef float f4v __attribute__((ext_vector_type(4)));
typedef float f16a __attribute__((ext_vector_type(16)));

__device__ __forceinline__ unsigned short f2us(float x){
    bf16 h = __float2bfloat16(x);
    return *reinterpret_cast<unsigned short*>(&h);
}
__device__ __forceinline__ unsigned int pack2(float a, float b){
    return (unsigned int)f2us(a) | ((unsigned int)f2us(b) << 16);
}
// async global->LDS, 16 B per lane; lds base must be wave-uniform
__device__ __forceinline__ void glds16(const unsigned short* g, unsigned short* lds_base){
    __builtin_amdgcn_global_load_lds(
        (const __attribute__((address_space(1))) unsigned int*)g,
        (__attribute__((address_space(3))) unsigned int*)lds_base, 16, 0, 0);
}

// ---------------------------------------------------------------------------
// Prep 1: fp32 -> bf16 bulk convert (x, proj_W)
// ---------------------------------------------------------------------------
__global__ void cvt_kernel(const float* __restrict__ src,
                           unsigned short* __restrict__ dst, int n4) {
    int i = blockIdx.x * 256 + threadIdx.x;
    if (i < n4) {
        float4 f = *(const float4*)(src + (size_t)i * 4);
        ushort4 o;
        o.x = f2us(f.x); o.y = f2us(f.y); o.z = f2us(f.z); o.w = f2us(f.w);
        *(ushort4*)(dst + (size_t)i * 4) = o;
    }
}

// ---------------------------------------------------------------------------
// Prep 2: transpose Wq/Wk/Wv [h][d][e] fp32 -> Wt [sel][h][e][d] bf16.
// ---------------------------------------------------------------------------
__global__ __launch_bounds__(256) void wt_kernel(
    const float* __restrict__ Wq, const float* __restrict__ Wk,
    const float* __restrict__ Wv, unsigned short* __restrict__ Wt)
{
    const int dt  = blockIdx.x;   // 16 d-tiles
    const int h   = blockIdx.y;   // 16
    const int sel = blockIdx.z;   // 3
    const float* W = (sel == 0) ? Wq : ((sel == 1) ? Wk : Wv);
    const float* Wh = W + (size_t)h * Dv * HDv;
    __shared__ float Tf[64][65];
    const int tid = threadIdx.x;
    for (int l = 0; l < 16; ++l) {
        int idx = tid + l * 256;
        int r = idx >> 6, e = idx & 63;
        Tf[r][e] = Wh[(size_t)(dt * 64 + r) * HDv + e];
    }
    __syncthreads();
    unsigned short* out = Wt + ((size_t)sel * Hv + h) * HDv * Dv;
    for (int l = 0; l < 16; ++l) {
        int idx = tid + l * 256;
        int e = idx >> 6, d = idx & 63;
        out[(size_t)e * Dv + dt * 64 + d] = f2us(Tf[d][e]);
    }
}

// ---------------------------------------------------------------------------
// Fused QKV GEMM, 256x256-tile 8-phase schedule (T1+T2+T3+T4+T5):
//   C[8192][3072] = x_bf . Wt^T, BK=64, 8 waves (2M x 4N), per-wave 128x64.
//   Changes this round:
//   - it==7 tail restage REMOVED (was refetching tiles 0/1: 49 MB garbage);
//     last-iter P4 gate tightened to vmcnt(0) (counted-wait semantics).
//   - q/k output layout -> [B*T][H*64] row-major; epilogue stages acc in the
//     (now dead) LDS buffers per-wave and stores 16B/lane full-line rows
//     (16 dwordx4 stores/thread vs 128 scalar shorts).
//   vT epilogue (direct 8B-chunk writes) unchanged.
// ---------------------------------------------------------------------------
__global__ __launch_bounds__(512, 2) void qkv_8ph(
    const unsigned short* __restrict__ xb, const unsigned short* __restrict__ Wc,
    const float* __restrict__ s_raw,
    unsigned short* __restrict__ q, unsigned short* __restrict__ k,
    unsigned short* __restrict__ vT)
{
    extern __shared__ unsigned short smem[];   // 65536 ushorts = 128 KiB
    // T1 remap: 384 = 8 xcd * 48 slots; per-XCD compact 4x12 strip
    const int lid  = blockIdx.x;
    const int xcd  = lid & 7;
    const int slot = lid >> 3;            // 0..47
    const int bm   = xcd * 4 + (slot & 3);   // 0..31
    const int bn   = slot >> 2;              // 0..11
    const int tid = threadIdx.x;
    const int w = tid >> 6, lane = tid & 63;
    const int wm = w >> 2, wn = w & 3;          // 2 x 4 wave grid
    const int n16 = lane & 15, quad = lane >> 4, l7 = lane & 7;

    const int row0 = bm * 256, col0 = bn * 256;

    // staging per-lane offsets: 8 lanes per 128B row, swizzled col chunk
    const int sr = lane >> 3;
    const int sc = ((lane & 7) ^ (sr & 7)) * 8;   // ushorts

    f4v acc[8][4];
    f4v zero = {0.f, 0.f, 0.f, 0.f};
    #pragma unroll
    for (int i = 0; i < 8; ++i)
        #pragma unroll
        for (int j = 0; j < 4; ++j) acc[i][j] = zero;

    s8v Ar[8][2];   // A frags: mi 0..7, kk 0..1
    s8v Br[4][2];   // B frags: ni 0..3, kk 0..1

    // LDS (ushort idx): buf b at b*32768; A at +0, B at +16384; halves 8192.
    auto stageA = [&](int b, int h, int tk){
        const unsigned short* g = xb + ((size_t)(row0 + h*128 + w*16 + sr)) * Dv + tk*64 + sc;
        unsigned short* l = smem + b*32768 + h*8192 + w*1024;
        glds16(g, l);
        glds16(g + 8*Dv, l + 512);
    };
    auto stageB = [&](int b, int h, int tk){
        const unsigned short* g = Wc + ((size_t)(col0 + h*128 + w*16 + sr)) * Dv + tk*64 + sc;
        unsigned short* l = smem + b*32768 + 16384 + h*8192 + w*1024;
        glds16(g, l);
        glds16(g + 8*Dv, l + 512);
    };
    auto readA = [&](int b, int mh){
        #pragma unroll
        for (int mi = 0; mi < 4; ++mi)
            #pragma unroll
            for (int kk = 0; kk < 2; ++kk)
                Ar[mh*4+mi][kk] = *(const s8v*)(smem + b*32768 + wm*8192
                    + ((mh*4+mi)*16 + n16) * 64 + (((kk*4 + quad) ^ l7) * 8));
    };
    auto readB = [&](int b, int nh){
        #pragma unroll
        for (int ni = 0; ni < 2; ++ni)
            #pragma unroll
            for (int kk = 0; kk < 2; ++kk)
                Br[nh*2+ni][kk] = *(const s8v*)(smem + b*32768 + 16384 + (wn>>1)*8192
                    + ((wn&1)*64 + (nh*2+ni)*16 + n16) * 64 + (((kk*4 + quad) ^ l7) * 8));
    };
    auto quadMM = [&](int mh, int nh){
        #pragma unroll
        for (int kk = 0; kk < 2; ++kk)
            #pragma unroll
            for (int mi = 0; mi < 4; ++mi)
                #pragma unroll
                for (int ni = 0; ni < 2; ++ni)
                    acc[mh*4+mi][nh*2+ni] = __builtin_amdgcn_mfma_f32_16x16x32_bf16(
                        Ar[mh*4+mi][kk], Br[nh*2+ni][kk], acc[mh*4+mi][nh*2+ni], 0, 0, 0);
    };

    // prologue: tiles 0 (buf0) and 1 (buf1); gate tile0, leave tile1 in flight
    stageA(0,0,0); stageA(0,1,0); stageB(0,0,0); stageB(0,1,0);
    stageA(1,0,1); stageA(1,1,1); stageB(1,0,1); stageB(1,1,1);
    asm volatile("s_waitcnt vmcnt(8)" ::: "memory");
    __builtin_amdgcn_s_barrier();

    #pragma unroll 1
    for (int it = 0; it < 8; ++it) {
        const bool nl = (it < 7);                 // not-last: stages exist
        const int t2 = 2*it + 2, t3 = 2*it + 3;   // only used when nl
        // P1: reads feed Q(0,0) of tile 2i (buf0)
        readA(0,0); readB(0,0);
        __builtin_amdgcn_s_barrier();
        __builtin_amdgcn_s_setprio(1); quadMM(0,0); __builtin_amdgcn_s_setprio(0);
        __builtin_amdgcn_s_barrier();
        // P2: Q(0,1); prefetch-read A[4..7] for P3/P4; then force all buf0 reads done
        readB(0,1); readA(0,1);
        __builtin_amdgcn_s_barrier();
        __builtin_amdgcn_s_setprio(1); quadMM(0,1); __builtin_amdgcn_s_setprio(0);
        asm volatile("s_waitcnt lgkmcnt(0)" ::: "memory");
        __builtin_amdgcn_s_barrier();
        // P3: Q(1,0); buf0 A-half0 free -> stage tile 2i+2
        if (nl) stageA(0,0,t2);
        __builtin_amdgcn_s_barrier();
        __builtin_amdgcn_s_setprio(1); quadMM(1,0); __builtin_amdgcn_s_setprio(0);
        __builtin_amdgcn_s_barrier();
        // P4: Q(1,1); gate so buf1 (tile 2i+1, staged prev iter) is landed.
        // On last iter there are no newer stages queued, so counted vmcnt(4)
        // would NOT force prev-iter P8 stages complete -> drain to 0 instead.
        if (nl) stageA(0,1,t2);
        __builtin_amdgcn_s_barrier();
        __builtin_amdgcn_s_setprio(1); quadMM(1,1); __builtin_amdgcn_s_setprio(0);
        if (nl) { asm volatile("s_waitcnt vmcnt(4)" ::: "memory"); }
        else    { asm volatile("s_waitcnt vmcnt(0)" ::: "memory"); }
        __builtin_amdgcn_s_barrier();
        // P5: tile 2i+1 (buf1) Q(0,0); stage buf0 B-half0
        readA(1,0); readB(1,0);
        if (nl) stageB(0,0,t2);
        __builtin_amdgcn_s_barrier();
        __builtin_amdgcn_s_setprio(1); quadMM(0,0); __builtin_amdgcn_s_setprio(0);
        __builtin_amdgcn_s_barrier();
        // P6: Q(0,1); stage buf0 B-half1; force all buf1 reads done
        readB(1,1); readA(1,1);
        if (nl) stageB(0,1,t2);
        __builtin_amdgcn_s_barrier();
        __builtin_amdgcn_s_setprio(1); quadMM(0,1); __builtin_amdgcn_s_setprio(0);
        asm volatile("s_waitcnt lgkmcnt(0)" ::: "memory");
        __builtin_amdgcn_s_barrier();
        // P7: Q(1,0); stage buf1 A halves (tile 2i+3)
        if (nl) { stageA(1,0,t3); stageA(1,1,t3); }
        __builtin_amdgcn_s_barrier();
        __builtin_amdgcn_s_setprio(1); quadMM(1,0); __builtin_amdgcn_s_setprio(0);
        __builtin_amdgcn_s_barrier();
        // P8: Q(1,1); stage buf1 B halves; gate so buf0 (tile 2i+2) is landed
        if (nl) { stageB(1,0,t3); stageB(1,1,t3); }
        __builtin_amdgcn_s_barrier();
        __builtin_amdgcn_s_setprio(1); quadMM(1,1); __builtin_amdgcn_s_setprio(0);
        if (nl) { asm volatile("s_waitcnt vmcnt(8)" ::: "memory"); }
        __builtin_amdgcn_s_barrier();
    }
    // After final P8 barrier: all waves' LDS reads done (P6 lgkmcnt(0)),
    // all glds16 drained (last-iter P4 vmcnt(0), no stages after).
    // -> LDS is safely reusable for the epilogue.

    // epilogue: per wave one (sel, h) slab of 128 rows x 64 cols
    const int sel = bn >> 2;
    const int h = (bn * 4 + wn) & 15;
    if (sel == 2) {
        // vT [b,h,e,t]: direct 8B-chunk writes (t-contiguous per lane)
        #pragma unroll
        for (int ni = 0; ni < 4; ++ni) {
            int e = ni * 16 + n16;
            #pragma unroll
            for (int mi = 0; mi < 8; ++mi) {
                int row = row0 + wm * 128 + mi * 16 + quad * 4;
                int bb_ = row >> 11, t = row & (Tv - 1);
                ushort4 o4;
                o4.x = f2us(acc[mi][ni][0]); o4.y = f2us(acc[mi][ni][1]);
                o4.z = f2us(acc[mi][ni][2]); o4.w = f2us(acc[mi][ni][3]);
                *(ushort4*)(vT + ((size_t)(bb_ * Hv + h) * HDv + e) * Tv + t) = o4;
            }
        }
    } else {
        // q/k in [B*T][1024] layout: stage bf16 tile in own 16KB LDS region,
        // then 16B/lane full-line stores (8 rows x 128 B per instruction).
        unsigned short* outp = (sel == 0) ? q : k;
        const float sc_h = (sel == 0) ? log1pf(expf(s_raw[h])) * 0.125f : 1.0f;
        unsigned short* ep = smem + w * 8192;
        const int colq = (bn & 3) * 256 + wn * 64;   // == h*64 within [0,1024)
        #pragma unroll
        for (int mi = 0; mi < 8; ++mi) {
            #pragma unroll
            for (int r = 0; r < 4; ++r) {
                const int lrow = mi * 16 + quad * 4 + r;
                const int t = (row0 + wm * 128 + lrow) & (Tv - 1);
                const float rs = (sel == 0) ? sc_h * __logf((float)(t + 1)) : 1.0f;
                #pragma unroll
                for (int ni = 0; ni < 4; ++ni)
                    ep[lrow * 64 + ni * 16 + n16] = f2us(acc[mi][ni][r] * rs);
            }
        }
        // same-wave LDS readback (compiler inserts lgkmcnt); no barrier needed
        #pragma unroll
        for (int i = 0; i < 16; ++i) {
            const int rrow = i * 8 + (lane >> 3);
            s8v vv = *(const s8v*)(ep + rrow * 64 + (lane & 7) * 8);
            *(s8v*)(outp + (size_t)(row0 + wm * 128 + rrow) * Dv + colq + (lane & 7) * 8) = vv;
        }
    }
}

// ---------------------------------------------------------------------------
// Flash attention, S^T formulation. LOAD-BALANCED: each block handles the
// q-tile pair (qtA, 15-qtA) -> uniform 17 s-steps/block, grid (8,64).
// q/k now in [B*T][H*64] layout; vT still [b,h,e,t].
// ---------------------------------------------------------------------------
__global__ __launch_bounds__(256) void attn_mfma(
    const unsigned short* __restrict__ q, const unsigned short* __restrict__ k,
    const unsigned short* __restrict__ vT, unsigned short* __restrict__ attn)
{
    const int bh = blockIdx.y;
    const int b = bh >> 4, h = bh & 15;
    const int tid = threadIdx.x;
    const int w = tid >> 6, lane = tid & 63;
    const int l31 = lane & 31, hi = lane >> 5;

    __shared__ __align__(16) unsigned short Ks[128][72];   // [s][e]
    __shared__ __align__(16) unsigned short VTs[64][136];  // [e][s]

    const size_t qkbase = (size_t)b * Tv * Dv + h * HDv;   // row-major [B*T][1024]
    const unsigned short* kb = k + qkbase;
    const unsigned short* vb = vT + (size_t)(b * Hv + h) * Tv * HDv;

    for (int phase = 0; phase < 2; ++phase) {
        const int qt = phase ? (15 - (int)blockIdx.x) : (int)blockIdx.x;
        const int qstrip = qt * 128 + w * 32;
        const int myq = qstrip + l31;

        // Q fragments (B-operand): e = 16*ks + 8*hi + j
        s8v qf[4];
        #pragma unroll
        for (int ks = 0; ks < 4; ++ks)
            qf[ks] = *(const s8v*)(q + qkbase + (size_t)myq * Dv + ks * 16 + hi * 8);

        f16a st[4], ot0, ot1;
        #pragma unroll
        for (int i = 0; i < 16; ++i) { ot0[i] = 0.f; ot1[i] = 0.f; }
        float lrun = 0.f;   // lane's half; partner (lane^32) holds the rest

        for (int ss = 0; ss <= qt; ++ss) {
            const int s0 = ss * 128;
            __syncthreads();                               // prev reads done
            #pragma unroll
            for (int l = 0; l < 4; ++l) {                  // K: 128 rows x 64e
                int idx = tid + l * 256;
                int r = idx >> 3, c = (idx & 7) * 8;
                *(ulonglong2*)(&Ks[r][c]) =
                    *(const ulonglong2*)(kb + (size_t)(s0 + r) * Dv + c);
            }
            #pragma unroll
            for (int l = 0; l < 4; ++l) {                  // V^T: 64 rows x 128s
                int idx = tid + l * 256;
                int e = idx >> 4, c = (idx & 15) * 8;
                *(ulonglong2*)(&VTs[e][c]) =
                    *(const ulonglong2*)(vb + (size_t)e * Tv + s0 + c);
            }
            __syncthreads();

            // S^T = K.Q^T : 4 s-subtiles x 4 ks
            #pragma unroll
            for (int mt = 0; mt < 4; ++mt)
                #pragma unroll
                for (int i = 0; i < 16; ++i) st[mt][i] = 0.f;
            #pragma unroll
            for (int ks = 0; ks < 4; ++ks) {
                #pragma unroll
                for (int mt = 0; mt < 4; ++mt) {
                    s8v a = *(const s8v*)(&Ks[32 * mt + l31][ks * 16 + hi * 8]);
                    st[mt] = __builtin_amdgcn_mfma_f32_32x32x16_bf16(a, qf[ks], st[mt], 0, 0, 0);
                }
            }
            // causal mask (diagonal block only): s = s0+32mt+srow vs q=myq
            if (s0 + 127 > qstrip) {
                #pragma unroll
                for (int mt = 0; mt < 4; ++mt)
                    #pragma unroll
                    for (int reg = 0; reg < 16; ++reg) {
                        int srow = (reg & 3) + 8 * (reg >> 2) + 4 * hi;
                        if (s0 + 32 * mt + srow > myq) st[mt][reg] = -1e30f;
                    }
            }
            // plain exp + partial sum
            float lsum = 0.f;
            #pragma unroll
            for (int mt = 0; mt < 4; ++mt)
                #pragma unroll
                for (int i = 0; i < 16; ++i) {
                    st[mt][i] = __expf(st[mt][i]);
                    lsum += st[mt][i];
                }
            lrun += lsum;

            // O^T += V^T.P^T in two 64-s halves (caps pk at 16 regs)
            #pragma unroll
            for (int half = 0; half < 2; ++half) {
                unsigned int pk[16];
                #pragma unroll
                for (int g = 0; g < 4; ++g) {
                    pk[2*g]       = pack2(st[2*half][4*g],     st[2*half][4*g+1]);
                    pk[2*g+1]     = pack2(st[2*half][4*g+2],   st[2*half][4*g+3]);
                    pk[8+2*g]     = pack2(st[2*half+1][4*g],   st[2*half+1][4*g+1]);
                    pk[8+2*g+1]   = pack2(st[2*half+1][4*g+2], st[2*half+1][4*g+3]);
                }
                #pragma unroll
                for (int ks4 = 0; ks4 < 4; ++ks4) {
                    const int ks = half * 4 + ks4;
                    const int base = (ks4 >> 1) * 8 + (ks4 & 1) * 4;
                    unsigned int v0 = hi ? pk[base]     : pk[base + 2];
                    unsigned int v1 = hi ? pk[base + 1] : pk[base + 3];
                    unsigned int r0 = (unsigned int)__shfl_xor((int)v0, 32);
                    unsigned int r1 = (unsigned int)__shfl_xor((int)v1, 32);
                    union { s8v v; unsigned int d[4]; } bf;
                    bf.d[0] = hi ? r0 : pk[base];
                    bf.d[1] = hi ? r1 : pk[base + 1];
                    bf.d[2] = hi ? pk[base + 2] : r0;
                    bf.d[3] = hi ? pk[base + 3] : r1;
                    s8v a0 = *(const s8v*)(&VTs[l31][ks * 16 + hi * 8]);
                    s8v a1 = *(const s8v*)(&VTs[32 + l31][ks * 16 + hi * 8]);
                    ot0 = __builtin_amdgcn_mfma_f32_32x32x16_bf16(a0, bf.v, ot0, 0, 0, 0);
                    ot1 = __builtin_amdgcn_mfma_f32_32x32x16_bf16(a1, bf.v, ot1, 0, 0, 0);
                }
            }
        }

        // epilogue: combine l halves, O^T[e][q]/l -> attn[b, t=myq, h*64+e]
        float ltot = lrun + __shfl_xor(lrun, 32);
        float inv = 1.0f / ltot;
        size_t obase = ((size_t)(b * Tv) + myq) * Dv + h * HDv;
        #pragma unroll
        for (int g = 0; g < 4; ++g) {
            ushort4 o4;
            o4.x = f2us(ot0[4*g]   * inv); o4.y = f2us(ot0[4*g+1] * inv);
            o4.z = f2us(ot0[4*g+2] * inv); o4.w = f2us(ot0[4*g+3] * inv);
            *(ushort4*)(attn + obase + 8 * g + 4 * hi) = o4;
            o4.x = f2us(ot1[4*g]   * inv); o4.y = f2us(ot1[4*g+1] * inv);
            o4.z = f2us(ot1[4*g+2] * inv); o4.w = f2us(ot1[4*g+3] * inv);
            *(ushort4*)(attn + obase + 32 + 8 * g + 4 * hi) = o4;
        }
    }
}

// ---------------------------------------------------------------------------
// Out projection, m97-style staging: out = attn . Wpb^T + bias (fp32 out).
// ---------------------------------------------------------------------------
__global__ __launch_bounds__(256) void proj_big(
    const unsigned short* __restrict__ attn, const unsigned short* __restrict__ Wb,
    const float* __restrict__ bias, float* __restrict__ out)
{
    const int bm = blockIdx.x;   // 64
    const int bn = blockIdx.y;   // 8
    const int tid = threadIdx.x;
    const int w = tid >> 6, lane = tid & 63;
    const int n16 = lane & 15, quad = lane >> 4;
    const int wm = w >> 1, wn = w & 1;

    __shared__ __align__(16) unsigned short As[128 * 64];
    __shared__ __align__(16) unsigned short Bs[128 * 64];

    f4v acc[4][4];
    f4v zero = {0.f, 0.f, 0.f, 0.f};
    #pragma unroll
    for (int i = 0; i < 4; ++i)
        #pragma unroll
        for (int j = 0; j < 4; ++j) acc[i][j] = zero;

    const int row0 = bm * 128, col0 = bn * 128;
    const int lr = lane >> 3, lc = (lane & 7) * 8;

    for (int k0 = 0; k0 < Dv; k0 += 64) {
        __syncthreads();
        #pragma unroll
        for (int i = 0; i < 4; ++i) {
            int rb = w * 32 + i * 8;
            glds16(attn + (size_t)(row0 + rb + lr) * Dv + k0 + lc, &As[rb * 64]);
            glds16(Wb   + (size_t)(col0 + rb + lr) * Dv + k0 + lc, &Bs[rb * 64]);
        }
        __syncthreads();
        #pragma unroll
        for (int ks = 0; ks < 2; ++ks) {
            s8v bfr[4];
            #pragma unroll
            for (int ni = 0; ni < 4; ++ni)
                bfr[ni] = *(const s8v*)(&Bs[(wn * 64 + ni * 16 + n16) * 64 + ks * 32 + quad * 8]);
            #pragma unroll
            for (int mi = 0; mi < 4; ++mi) {
                s8v afr = *(const s8v*)(&As[(wm * 64 + mi * 16 + n16) * 64 + ks * 32 + quad * 8]);
                #pragma unroll
                for (int ni = 0; ni < 4; ++ni)
                    acc[mi][ni] = __builtin_amdgcn_mfma_f32_16x16x32_bf16(afr, bfr[ni], acc[mi][ni], 0, 0, 0);
            }
        }
    }
    #pragma unroll
    for (int ni = 0; ni < 4; ++ni) {
        int n = col0 + wn * 64 + ni * 16 + n16;
        float bn_ = bias[n];
        #pragma unroll
        for (int mi = 0; mi < 4; ++mi) {
            #pragma unroll
            for (int r = 0; r < 4; ++r) {
                int m = row0 + wm * 64 + mi * 16 + quad * 4 + r;
                out[(size_t)m * Dv + n] = acc[mi][ni][r] + bn_;
            }
        }
    }
}

extern "C" void kernel_launch(void* const* d_in, const int* in_sizes, int n_in,
                              void* d_out, int out_size, void* d_ws, size_t ws_size,
                              hipStream_t stream) {
    const float* x     = (const float*)d_in[0];
    const float* Wq    = (const float*)d_in[1];
    const float* Wk    = (const float*)d_in[2];
    const float* Wv    = (const float*)d_in[3];
    const float* s_raw = (const float*)d_in[4];
    const float* projW = (const float*)d_in[5];
    const float* projb = (const float*)d_in[6];
    float* out = (float*)d_out;

    const size_t nx  = (size_t)Mv * Dv;              // 8.4M (x_bf, reused as attn)
    const size_t nqk = (size_t)Bv * Hv * Tv * HDv;   // 8.4M each
    unsigned short* x_bf = (unsigned short*)d_ws;
    unsigned short* qb   = x_bf + nx;
    unsigned short* kb   = qb + nqk;
    unsigned short* vTb  = kb + nqk;
    unsigned short* Wt   = vTb + nqk;                // 3072 x 1024
    unsigned short* Wpb  = Wt + (size_t)3 * Hv * HDv * Dv;
    unsigned short* attn = x_bf;                     // alias: x_bf dead after qkv

    static int cfg = 0;
    if (!cfg) {
        (void)hipFuncSetAttribute((const void*)qkv_8ph,
                                  hipFuncAttributeMaxDynamicSharedMemorySize, 131072);
        cfg = 1;
    }

    cvt_kernel<<<(int)(nx / 4 / 256), 256, 0, stream>>>(x, x_bf, (int)(nx / 4));
    cvt_kernel<<<(int)((size_t)Dv * Dv / 4 / 256), 256, 0, stream>>>(projW, Wpb, Dv * Dv / 4);
    wt_kernel<<<dim3(16, 16, 3), 256, 0, stream>>>(Wq, Wk, Wv, Wt);
    qkv_8ph<<<dim3(384), 512, 131072, stream>>>(x_bf, Wt, s_raw, qb, kb, vTb);
    attn_mfma<<<dim3(8, Bv * Hv), 256, 0, stream>>>(qb, kb, vTb, attn);
    proj_big<<<dim3(Mv / 128, Dv / 128), 256, 0, stream>>>(attn, Wpb, projb, out);
}

// Round 6
// 266.114 us; speedup vs baseline: 1.0753x; 1.0753x over previous
//
#include <hip/hip_runtime.h>
#include <hip/hip_bf16.h>

#define Bv 4
#define Tv 2048
#define Dv 1024
#define Hv 16
#define HDv 64
#define Mv (Bv*Tv)   // 8192

typedef __hip_bfloat16 bf16;
typedef short s8v __attribute__((ext_vector_type(8)));
typedef float f4v __attribute__((ext_vector_type(4)));
typedef float f16a __attribute__((ext_vector_type(16)));

__device__ __forceinline__ unsigned short f2us(float x){
    bf16 h = __float2bfloat16(x);
    return *reinterpret_cast<unsigned short*>(&h);
}
__device__ __forceinline__ unsigned int pack2(float a, float b){
    return (unsigned int)f2us(a) | ((unsigned int)f2us(b) << 16);
}
// async global->LDS, 16 B per lane; lds base must be wave-uniform
__device__ __forceinline__ void glds16(const unsigned short* g, unsigned short* lds_base){
    __builtin_amdgcn_global_load_lds(
        (const __attribute__((address_space(1))) unsigned int*)g,
        (__attribute__((address_space(3))) unsigned int*)lds_base, 16, 0, 0);
}

// ---------------------------------------------------------------------------
// Prep 1: fp32 -> bf16 bulk convert (x, proj_W)
// ---------------------------------------------------------------------------
__global__ void cvt_kernel(const float* __restrict__ src,
                           unsigned short* __restrict__ dst, int n4) {
    int i = blockIdx.x * 256 + threadIdx.x;
    if (i < n4) {
        float4 f = *(const float4*)(src + (size_t)i * 4);
        ushort4 o;
        o.x = f2us(f.x); o.y = f2us(f.y); o.z = f2us(f.z); o.w = f2us(f.w);
        *(ushort4*)(dst + (size_t)i * 4) = o;
    }
}

// ---------------------------------------------------------------------------
// Prep 2: transpose Wq/Wk/Wv [h][d][e] fp32 -> Wt [sel][h][e][d] bf16.
// ---------------------------------------------------------------------------
__global__ __launch_bounds__(256) void wt_kernel(
    const float* __restrict__ Wq, const float* __restrict__ Wk,
    const float* __restrict__ Wv, unsigned short* __restrict__ Wt)
{
    const int dt  = blockIdx.x;   // 16 d-tiles
    const int h   = blockIdx.y;   // 16
    const int sel = blockIdx.z;   // 3
    const float* W = (sel == 0) ? Wq : ((sel == 1) ? Wk : Wv);
    const float* Wh = W + (size_t)h * Dv * HDv;
    __shared__ float Tf[64][65];
    const int tid = threadIdx.x;
    for (int l = 0; l < 16; ++l) {
        int idx = tid + l * 256;
        int r = idx >> 6, e = idx & 63;
        Tf[r][e] = Wh[(size_t)(dt * 64 + r) * HDv + e];
    }
    __syncthreads();
    unsigned short* out = Wt + ((size_t)sel * Hv + h) * HDv * Dv;
    for (int l = 0; l < 16; ++l) {
        int idx = tid + l * 256;
        int e = idx >> 6, d = idx & 63;
        out[(size_t)e * Dv + dt * 64 + d] = f2us(Tf[d][e]);
    }
}

// ---------------------------------------------------------------------------
// Fused QKV GEMM, 256x256-tile 8-phase schedule (T1+T2+T3+T4+T5):
//   C[8192][3072] = x_bf . Wt^T, BK=64, 8 waves (2M x 4N), per-wave 128x64.
//   This round:
//   - Quadrant order per tile: Q(0,0)->Q(1,0)->Q(1,1)->Q(0,1): LDS reads
//     spread 12/8/4/0 b128 per phase (was 12/12/0/0) so every phase carries
//     both reads and MFMA (lockstep barrier schedule serializes read bursts).
//   - Epilogue LDS staging XOR-swizzled (col ^= quad*16 write / matching
//     read key): write banks 32-wide 2-deep (free), was 8-way conflicted.
// ---------------------------------------------------------------------------
__global__ __launch_bounds__(512, 2) void qkv_8ph(
    const unsigned short* __restrict__ xb, const unsigned short* __restrict__ Wc,
    const float* __restrict__ s_raw,
    unsigned short* __restrict__ q, unsigned short* __restrict__ k,
    unsigned short* __restrict__ vT)
{
    extern __shared__ unsigned short smem[];   // 65536 ushorts = 128 KiB
    // T1 remap: 384 = 8 xcd * 48 slots; per-XCD compact 4x12 strip
    const int lid  = blockIdx.x;
    const int xcd  = lid & 7;
    const int slot = lid >> 3;            // 0..47
    const int bm   = xcd * 4 + (slot & 3);   // 0..31
    const int bn   = slot >> 2;              // 0..11
    const int tid = threadIdx.x;
    const int w = tid >> 6, lane = tid & 63;
    const int wm = w >> 2, wn = w & 3;          // 2 x 4 wave grid
    const int n16 = lane & 15, quad = lane >> 4, l7 = lane & 7;

    const int row0 = bm * 256, col0 = bn * 256;

    // staging per-lane offsets: 8 lanes per 128B row, swizzled col chunk
    const int sr = lane >> 3;
    const int sc = ((lane & 7) ^ (sr & 7)) * 8;   // ushorts

    f4v acc[8][4];
    f4v zero = {0.f, 0.f, 0.f, 0.f};
    #pragma unroll
    for (int i = 0; i < 8; ++i)
        #pragma unroll
        for (int j = 0; j < 4; ++j) acc[i][j] = zero;

    s8v Ar[8][2];   // A frags: mi 0..7, kk 0..1
    s8v Br[4][2];   // B frags: ni 0..3, kk 0..1

    // LDS (ushort idx): buf b at b*32768; A at +0, B at +16384; halves 8192.
    auto stageA = [&](int b, int h, int tk){
        const unsigned short* g = xb + ((size_t)(row0 + h*128 + w*16 + sr)) * Dv + tk*64 + sc;
        unsigned short* l = smem + b*32768 + h*8192 + w*1024;
        glds16(g, l);
        glds16(g + 8*Dv, l + 512);
    };
    auto stageB = [&](int b, int h, int tk){
        const unsigned short* g = Wc + ((size_t)(col0 + h*128 + w*16 + sr)) * Dv + tk*64 + sc;
        unsigned short* l = smem + b*32768 + 16384 + h*8192 + w*1024;
        glds16(g, l);
        glds16(g + 8*Dv, l + 512);
    };
    auto readA = [&](int b, int mh){
        #pragma unroll
        for (int mi = 0; mi < 4; ++mi)
            #pragma unroll
            for (int kk = 0; kk < 2; ++kk)
                Ar[mh*4+mi][kk] = *(const s8v*)(smem + b*32768 + wm*8192
                    + ((mh*4+mi)*16 + n16) * 64 + (((kk*4 + quad) ^ l7) * 8));
    };
    auto readB = [&](int b, int nh){
        #pragma unroll
        for (int ni = 0; ni < 2; ++ni)
            #pragma unroll
            for (int kk = 0; kk < 2; ++kk)
                Br[nh*2+ni][kk] = *(const s8v*)(smem + b*32768 + 16384 + (wn>>1)*8192
                    + ((wn&1)*64 + (nh*2+ni)*16 + n16) * 64 + (((kk*4 + quad) ^ l7) * 8));
    };
    auto quadMM = [&](int mh, int nh){
        #pragma unroll
        for (int kk = 0; kk < 2; ++kk)
            #pragma unroll
            for (int mi = 0; mi < 4; ++mi)
                #pragma unroll
                for (int ni = 0; ni < 2; ++ni)
                    acc[mh*4+mi][nh*2+ni] = __builtin_amdgcn_mfma_f32_16x16x32_bf16(
                        Ar[mh*4+mi][kk], Br[nh*2+ni][kk], acc[mh*4+mi][nh*2+ni], 0, 0, 0);
    };

    // prologue: tiles 0 (buf0) and 1 (buf1); gate tile0, leave tile1 in flight
    stageA(0,0,0); stageA(0,1,0); stageB(0,0,0); stageB(0,1,0);
    stageA(1,0,1); stageA(1,1,1); stageB(1,0,1); stageB(1,1,1);
    asm volatile("s_waitcnt vmcnt(8)" ::: "memory");
    __builtin_amdgcn_s_barrier();

    #pragma unroll 1
    for (int it = 0; it < 8; ++it) {
        const bool nl = (it < 7);                 // not-last: stages exist
        const int t2 = 2*it + 2, t3 = 2*it + 3;   // only used when nl
        // ---- tile 2i (buf0): quadrant order (0,0)(1,0)(1,1)(0,1) ----
        // P1: A-low + B-low [12 reads]; MFMA Q(0,0)
        readA(0,0); readB(0,0);
        __builtin_amdgcn_s_barrier();
        __builtin_amdgcn_s_setprio(1); quadMM(0,0); __builtin_amdgcn_s_setprio(0);
        __builtin_amdgcn_s_barrier();
        // P2: A-high [8 reads]; MFMA Q(1,0)
        readA(0,1);
        __builtin_amdgcn_s_barrier();
        __builtin_amdgcn_s_setprio(1); quadMM(1,0); __builtin_amdgcn_s_setprio(0);
        __builtin_amdgcn_s_barrier();
        // P3: B-high [4 reads] + stage A0 of tile t2; MFMA Q(1,1)
        readB(0,1);
        if (nl) stageA(0,0,t2);
        __builtin_amdgcn_s_barrier();
        __builtin_amdgcn_s_setprio(1); quadMM(1,1); __builtin_amdgcn_s_setprio(0);
        asm volatile("s_waitcnt lgkmcnt(0)" ::: "memory");
        __builtin_amdgcn_s_barrier();
        // P4: stage A1; MFMA Q(0,1) (Ar/Br already in regs); gate buf1 landed.
        // Last iter: no newer stages queued -> drain to 0 (counted semantics).
        if (nl) stageA(0,1,t2);
        __builtin_amdgcn_s_barrier();
        __builtin_amdgcn_s_setprio(1); quadMM(0,1); __builtin_amdgcn_s_setprio(0);
        if (nl) { asm volatile("s_waitcnt vmcnt(4)" ::: "memory"); }
        else    { asm volatile("s_waitcnt vmcnt(0)" ::: "memory"); }
        __builtin_amdgcn_s_barrier();
        // ---- tile 2i+1 (buf1) ----
        // P5: A-low + B-low; stage buf0 B0; MFMA Q(0,0)
        readA(1,0); readB(1,0);
        if (nl) stageB(0,0,t2);
        __builtin_amdgcn_s_barrier();
        __builtin_amdgcn_s_setprio(1); quadMM(0,0); __builtin_amdgcn_s_setprio(0);
        __builtin_amdgcn_s_barrier();
        // P6: A-high; stage buf0 B1; MFMA Q(1,0)
        readA(1,1);
        if (nl) stageB(0,1,t2);
        __builtin_amdgcn_s_barrier();
        __builtin_amdgcn_s_setprio(1); quadMM(1,0); __builtin_amdgcn_s_setprio(0);
        __builtin_amdgcn_s_barrier();
        // P7: B-high; stage buf1 A halves (tile t3); MFMA Q(1,1)
        readB(1,1);
        if (nl) { stageA(1,0,t3); stageA(1,1,t3); }
        __builtin_amdgcn_s_barrier();
        __builtin_amdgcn_s_setprio(1); quadMM(1,1); __builtin_amdgcn_s_setprio(0);
        asm volatile("s_waitcnt lgkmcnt(0)" ::: "memory");
        __builtin_amdgcn_s_barrier();
        // P8: stage buf1 B halves; MFMA Q(0,1); gate buf0 (tile t2) landed
        if (nl) { stageB(1,0,t3); stageB(1,1,t3); }
        __builtin_amdgcn_s_barrier();
        __builtin_amdgcn_s_setprio(1); quadMM(0,1); __builtin_amdgcn_s_setprio(0);
        if (nl) { asm volatile("s_waitcnt vmcnt(8)" ::: "memory"); }
        __builtin_amdgcn_s_barrier();
    }
    // After final P8 barrier: all LDS reads retired (per-phase dataflow +
    // P7 lgkm0), all glds16 drained (last-iter P4 vmcnt(0), no stages after).
    // -> LDS safely reusable for the epilogue.

    // epilogue: per wave one (sel, h) slab of 128 rows x 64 cols
    const int sel = bn >> 2;
    const int h = (bn * 4 + wn) & 15;
    if (sel == 2) {
        // vT [b,h,e,t]: direct 8B-chunk writes (t-contiguous per lane)
        #pragma unroll
        for (int ni = 0; ni < 4; ++ni) {
            int e = ni * 16 + n16;
            #pragma unroll
            for (int mi = 0; mi < 8; ++mi) {
                int row = row0 + wm * 128 + mi * 16 + quad * 4;
                int bb_ = row >> 11, t = row & (Tv - 1);
                ushort4 o4;
                o4.x = f2us(acc[mi][ni][0]); o4.y = f2us(acc[mi][ni][1]);
                o4.z = f2us(acc[mi][ni][2]); o4.w = f2us(acc[mi][ni][3]);
                *(ushort4*)(vT + ((size_t)(bb_ * Hv + h) * HDv + e) * Tv + t) = o4;
            }
        }
    } else {
        // q/k in [B*T][1024] layout: stage bf16 tile in own 16KB LDS region
        // (XOR-swizzled: col ^ quad*16 -> 32 banks, 2 lanes each = free),
        // then 16B/lane full-line stores (8 rows x 128 B per instruction).
        unsigned short* outp = (sel == 0) ? q : k;
        const float sc_h = (sel == 0) ? log1pf(expf(s_raw[h])) * 0.125f : 1.0f;
        unsigned short* ep = smem + w * 8192;
        const int colq = (bn & 3) * 256 + wn * 64;   // == h*64 within [0,1024)
        #pragma unroll
        for (int mi = 0; mi < 8; ++mi) {
            #pragma unroll
            for (int r = 0; r < 4; ++r) {
                const int lrow = mi * 16 + quad * 4 + r;
                const int t = (row0 + wm * 128 + lrow) & (Tv - 1);
                const float rs = (sel == 0) ? sc_h * __logf((float)(t + 1)) : 1.0f;
                #pragma unroll
                for (int ni = 0; ni < 4; ++ni)
                    ep[lrow * 64 + ((ni * 16 + n16) ^ (quad * 16))] = f2us(acc[mi][ni][r] * rs);
            }
        }
        // same-wave LDS readback (compiler inserts lgkmcnt); no barrier
        // needed. Read key from row: quad_of_writer = (rrow>>2)&3; XOR twice
        // cancels, so each lane's 16B are original cols (lane&7)*8..+8.
        #pragma unroll
        for (int i = 0; i < 16; ++i) {
            const int rrow = i * 8 + (lane >> 3);
            const int key = ((rrow >> 2) & 3) * 16;
            s8v vv = *(const s8v*)(ep + rrow * 64 + (((lane & 7) * 8) ^ key));
            *(s8v*)(outp + (size_t)(row0 + wm * 128 + rrow) * Dv + colq + (lane & 7) * 8) = vv;
        }
    }
}

// ---------------------------------------------------------------------------
// Flash attention, S^T formulation. LOAD-BALANCED: each block handles the
// q-tile pair (qtA, 15-qtA) -> uniform 17 s-steps/block, grid (8,64).
// q/k in [B*T][H*64] layout; vT [b,h,e,t].
// ---------------------------------------------------------------------------
__global__ __launch_bounds__(256) void attn_mfma(
    const unsigned short* __restrict__ q, const unsigned short* __restrict__ k,
    const unsigned short* __restrict__ vT, unsigned short* __restrict__ attn)
{
    const int bh = blockIdx.y;
    const int b = bh >> 4, h = bh & 15;
    const int tid = threadIdx.x;
    const int w = tid >> 6, lane = tid & 63;
    const int l31 = lane & 31, hi = lane >> 5;

    __shared__ __align__(16) unsigned short Ks[128][72];   // [s][e]
    __shared__ __align__(16) unsigned short VTs[64][136];  // [e][s]

    const size_t qkbase = (size_t)b * Tv * Dv + h * HDv;   // row-major [B*T][1024]
    const unsigned short* kb = k + qkbase;
    const unsigned short* vb = vT + (size_t)(b * Hv + h) * Tv * HDv;

    for (int phase = 0; phase < 2; ++phase) {
        const int qt = phase ? (15 - (int)blockIdx.x) : (int)blockIdx.x;
        const int qstrip = qt * 128 + w * 32;
        const int myq = qstrip + l31;

        // Q fragments (B-operand): e = 16*ks + 8*hi + j
        s8v qf[4];
        #pragma unroll
        for (int ks = 0; ks < 4; ++ks)
            qf[ks] = *(const s8v*)(q + qkbase + (size_t)myq * Dv + ks * 16 + hi * 8);

        f16a st[4], ot0, ot1;
        #pragma unroll
        for (int i = 0; i < 16; ++i) { ot0[i] = 0.f; ot1[i] = 0.f; }
        float lrun = 0.f;   // lane's half; partner (lane^32) holds the rest

        for (int ss = 0; ss <= qt; ++ss) {
            const int s0 = ss * 128;
            __syncthreads();                               // prev reads done
            #pragma unroll
            for (int l = 0; l < 4; ++l) {                  // K: 128 rows x 64e
                int idx = tid + l * 256;
                int r = idx >> 3, c = (idx & 7) * 8;
                *(ulonglong2*)(&Ks[r][c]) =
                    *(const ulonglong2*)(kb + (size_t)(s0 + r) * Dv + c);
            }
            #pragma unroll
            for (int l = 0; l < 4; ++l) {                  // V^T: 64 rows x 128s
                int idx = tid + l * 256;
                int e = idx >> 4, c = (idx & 15) * 8;
                *(ulonglong2*)(&VTs[e][c]) =
                    *(const ulonglong2*)(vb + (size_t)e * Tv + s0 + c);
            }
            __syncthreads();

            // S^T = K.Q^T : 4 s-subtiles x 4 ks
            #pragma unroll
            for (int mt = 0; mt < 4; ++mt)
                #pragma unroll
                for (int i = 0; i < 16; ++i) st[mt][i] = 0.f;
            #pragma unroll
            for (int ks = 0; ks < 4; ++ks) {
                #pragma unroll
                for (int mt = 0; mt < 4; ++mt) {
                    s8v a = *(const s8v*)(&Ks[32 * mt + l31][ks * 16 + hi * 8]);
                    st[mt] = __builtin_amdgcn_mfma_f32_32x32x16_bf16(a, qf[ks], st[mt], 0, 0, 0);
                }
            }
            // causal mask (diagonal block only): s = s0+32mt+srow vs q=myq
            if (s0 + 127 > qstrip) {
                #pragma unroll
                for (int mt = 0; mt < 4; ++mt)
                    #pragma unroll
                    for (int reg = 0; reg < 16; ++reg) {
                        int srow = (reg & 3) + 8 * (reg >> 2) + 4 * hi;
                        if (s0 + 32 * mt + srow > myq) st[mt][reg] = -1e30f;
                    }
            }
            // plain exp + partial sum
            float lsum = 0.f;
            #pragma unroll
            for (int mt = 0; mt < 4; ++mt)
                #pragma unroll
                for (int i = 0; i < 16; ++i) {
                    st[mt][i] = __expf(st[mt][i]);
                    lsum += st[mt][i];
                }
            lrun += lsum;

            // O^T += V^T.P^T in two 64-s halves (caps pk at 16 regs)
            #pragma unroll
            for (int half = 0; half < 2; ++half) {
                unsigned int pk[16];
                #pragma unroll
                for (int g = 0; g < 4; ++g) {
                    pk[2*g]       = pack2(st[2*half][4*g],     st[2*half][4*g+1]);
                    pk[2*g+1]     = pack2(st[2*half][4*g+2],   st[2*half][4*g+3]);
                    pk[8+2*g]     = pack2(st[2*half+1][4*g],   st[2*half+1][4*g+1]);
                    pk[8+2*g+1]   = pack2(st[2*half+1][4*g+2], st[2*half+1][4*g+3]);
                }
                #pragma unroll
                for (int ks4 = 0; ks4 < 4; ++ks4) {
                    const int ks = half * 4 + ks4;
                    const int base = (ks4 >> 1) * 8 + (ks4 & 1) * 4;
                    unsigned int v0 = hi ? pk[base]     : pk[base + 2];
                    unsigned int v1 = hi ? pk[base + 1] : pk[base + 3];
                    unsigned int r0 = (unsigned int)__shfl_xor((int)v0, 32);
                    unsigned int r1 = (unsigned int)__shfl_xor((int)v1, 32);
                    union { s8v v; unsigned int d[4]; } bf;
                    bf.d[0] = hi ? r0 : pk[base];
                    bf.d[1] = hi ? r1 : pk[base + 1];
                    bf.d[2] = hi ? pk[base + 2] : r0;
                    bf.d[3] = hi ? pk[base + 3] : r1;
                    s8v a0 = *(const s8v*)(&VTs[l31][ks * 16 + hi * 8]);
                    s8v a1 = *(const s8v*)(&VTs[32 + l31][ks * 16 + hi * 8]);
                    ot0 = __builtin_amdgcn_mfma_f32_32x32x16_bf16(a0, bf.v, ot0, 0, 0, 0);
                    ot1 = __builtin_amdgcn_mfma_f32_32x32x16_bf16(a1, bf.v, ot1, 0, 0, 0);
                }
            }
        }

        // epilogue: combine l halves, O^T[e][q]/l -> attn[b, t=myq, h*64+e]
        float ltot = lrun + __shfl_xor(lrun, 32);
        float inv = 1.0f / ltot;
        size_t obase = ((size_t)(b * Tv) + myq) * Dv + h * HDv;
        #pragma unroll
        for (int g = 0; g < 4; ++g) {
            ushort4 o4;
            o4.x = f2us(ot0[4*g]   * inv); o4.y = f2us(ot0[4*g+1] * inv);
            o4.z = f2us(ot0[4*g+2] * inv); o4.w = f2us(ot0[4*g+3] * inv);
            *(ushort4*)(attn + obase + 8 * g + 4 * hi) = o4;
            o4.x = f2us(ot1[4*g]   * inv); o4.y = f2us(ot1[4*g+1] * inv);
            o4.z = f2us(ot1[4*g+2] * inv); o4.w = f2us(ot1[4*g+3] * inv);
            *(ushort4*)(attn + obase + 32 + 8 * g + 4 * hi) = o4;
        }
    }
}

// ---------------------------------------------------------------------------
// Out projection, m97-style staging: out = attn . Wpb^T + bias (fp32 out).
// ---------------------------------------------------------------------------
__global__ __launch_bounds__(256) void proj_big(
    const unsigned short* __restrict__ attn, const unsigned short* __restrict__ Wb,
    const float* __restrict__ bias, float* __restrict__ out)
{
    const int bm = blockIdx.x;   // 64
    const int bn = blockIdx.y;   // 8
    const int tid = threadIdx.x;
    const int w = tid >> 6, lane = tid & 63;
    const int n16 = lane & 15, quad = lane >> 4;
    const int wm = w >> 1, wn = w & 1;

    __shared__ __align__(16) unsigned short As[128 * 64];
    __shared__ __align__(16) unsigned short Bs[128 * 64];

    f4v acc[4][4];
    f4v zero = {0.f, 0.f, 0.f, 0.f};
    #pragma unroll
    for (int i = 0; i < 4; ++i)
        #pragma unroll
        for (int j = 0; j < 4; ++j) acc[i][j] = zero;

    const int row0 = bm * 128, col0 = bn * 128;
    const int lr = lane >> 3, lc = (lane & 7) * 8;

    for (int k0 = 0; k0 < Dv; k0 += 64) {
        __syncthreads();
        #pragma unroll
        for (int i = 0; i < 4; ++i) {
            int rb = w * 32 + i * 8;
            glds16(attn + (size_t)(row0 + rb + lr) * Dv + k0 + lc, &As[rb * 64]);
            glds16(Wb   + (size_t)(col0 + rb + lr) * Dv + k0 + lc, &Bs[rb * 64]);
        }
        __syncthreads();
        #pragma unroll
        for (int ks = 0; ks < 2; ++ks) {
            s8v bfr[4];
            #pragma unroll
            for (int ni = 0; ni < 4; ++ni)
                bfr[ni] = *(const s8v*)(&Bs[(wn * 64 + ni * 16 + n16) * 64 + ks * 32 + quad * 8]);
            #pragma unroll
            for (int mi = 0; mi < 4; ++mi) {
                s8v afr = *(const s8v*)(&As[(wm * 64 + mi * 16 + n16) * 64 + ks * 32 + quad * 8]);
                #pragma unroll
                for (int ni = 0; ni < 4; ++ni)
                    acc[mi][ni] = __builtin_amdgcn_mfma_f32_16x16x32_bf16(afr, bfr[ni], acc[mi][ni], 0, 0, 0);
            }
        }
    }
    #pragma unroll
    for (int ni = 0; ni < 4; ++ni) {
        int n = col0 + wn * 64 + ni * 16 + n16;
        float bn_ = bias[n];
        #pragma unroll
        for (int mi = 0; mi < 4; ++mi) {
            #pragma unroll
            for (int r = 0; r < 4; ++r) {
                int m = row0 + wm * 64 + mi * 16 + quad * 4 + r;
                out[(size_t)m * Dv + n] = acc[mi][ni][r] + bn_;
            }
        }
    }
}

extern "C" void kernel_launch(void* const* d_in, const int* in_sizes, int n_in,
                              void* d_out, int out_size, void* d_ws, size_t ws_size,
                              hipStream_t stream) {
    const float* x     = (const float*)d_in[0];
    const float* Wq    = (const float*)d_in[1];
    const float* Wk    = (const float*)d_in[2];
    const float* Wv    = (const float*)d_in[3];
    const float* s_raw = (const float*)d_in[4];
    const float* projW = (const float*)d_in[5];
    const float* projb = (const float*)d_in[6];
    float* out = (float*)d_out;

    const size_t nx  = (size_t)Mv * Dv;              // 8.4M (x_bf, reused as attn)
    const size_t nqk = (size_t)Bv * Hv * Tv * HDv;   // 8.4M each
    unsigned short* x_bf = (unsigned short*)d_ws;
    unsigned short* qb   = x_bf + nx;
    unsigned short* kb   = qb + nqk;
    unsigned short* vTb  = kb + nqk;
    unsigned short* Wt   = vTb + nqk;                // 3072 x 1024
    unsigned short* Wpb  = Wt + (size_t)3 * Hv * HDv * Dv;
    unsigned short* attn = x_bf;                     // alias: x_bf dead after qkv

    static int cfg = 0;
    if (!cfg) {
        (void)hipFuncSetAttribute((const void*)qkv_8ph,
                                  hipFuncAttributeMaxDynamicSharedMemorySize, 131072);
        cfg = 1;
    }

    cvt_kernel<<<(int)(nx / 4 / 256), 256, 0, stream>>>(x, x_bf, (int)(nx / 4));
    cvt_kernel<<<(int)((size_t)Dv * Dv / 4 / 256), 256, 0, stream>>>(projW, Wpb, Dv * Dv / 4);
    wt_kernel<<<dim3(16, 16, 3), 256, 0, stream>>>(Wq, Wk, Wv, Wt);
    qkv_8ph<<<dim3(384), 512, 131072, stream>>>(x_bf, Wt, s_raw, qb, kb, vTb);
    attn_mfma<<<dim3(8, Bv * Hv), 256, 0, stream>>>(qb, kb, vTb, attn);
    proj_big<<<dim3(Mv / 128, Dv / 128), 256, 0, stream>>>(attn, Wpb, projb, out);
}